// Round 3
// baseline (394.034 us; speedup 1.0000x reference)
//
#include <hip/hip_runtime.h>
#include <hip/hip_bf16.h>

// Head-axis-softmax SDPA, B=2 S=2048 N=16 D=64, fp32 in/out.
// softmax over HEADS (n) -> local per (b,q,k).
//
// R7: two-pass factorization (R6) with the exp fixed + LDS-free pass2.
// R6 diagnosis: exp2f/__expf lower to the multi-instruction OCML path
// (~940 VALU cyc/tile vs ~240 expected) -> every structure plateaued at
// the exp-VALU throughput floor. Fixes:
//   1. __builtin_amdgcn_exp2f (single v_exp_f32) everywhere.
//   2. pass2 computes S^T = mfma(K,Q) so each lane holds a q-row of scores;
//      v_cvt_pk_bf16_f32 + v_permlane32_swap_b32 build PV A-frags entirely
//      in-register (no LDS W tile, no ds round-trip, no bank conflicts).
//   3. pass1 stores Zr TRANSPOSED (Zr_t[b][k][q], via wave-private LDS
//      32x33 transpose) so pass2's zr loads are coalesced in S^T layout.
//   4. pass1 head-loop fully unrolled for load pipelining.

#define B_ 2
#define S_ 2048
#define N_ 16
#define D_ 64
#define TQ 32
#define TK 32

typedef __bf16 bf16x4 __attribute__((ext_vector_type(4)));
typedef __bf16 bf16x8 __attribute__((ext_vector_type(8)));
typedef float  f32x16 __attribute__((ext_vector_type(16)));
typedef unsigned int uint32x4 __attribute__((ext_vector_type(4)));

// scale folded into Q at conversion: 1/sqrt(64) * log2(e)
#define QSCALE 0.18033688011112042f

static __device__ __forceinline__ unsigned int cvt_pk_bf16(float a, float b) {
    // dst low16 = bf16(a), high16 = bf16(b)
    unsigned int r;
    asm("v_cvt_pk_bf16_f32 %0, %1, %2" : "=v"(r) : "v"(a), "v"(b));
    return r;
}
static __device__ __forceinline__ void permlane_swap(unsigned int& a, unsigned int& b) {
    // exchanges a's lanes[32:63] with b's lanes[0:31]
    asm("v_permlane32_swap_b32 %0, %1" : "+v"(a), "+v"(b));
}

// ---------------------------------------------------------------------------
// Pre-pass 1: Q,K [b,s,n,d] f32 -> [b,n,s,d] bf16. Both sides coalesced.
// Q additionally pre-scaled by QSCALE so main kernels use exp2 directly.
// ---------------------------------------------------------------------------
__global__ __launch_bounds__(256) void cvt_qk_kernel(
    const float* __restrict__ Qf, const float* __restrict__ Kf,
    __bf16* __restrict__ Qb, __bf16* __restrict__ Kb)
{
    const int z = blockIdx.z;                  // 0..2B-1: first B -> Q, rest -> K
    const float* src = (z < B_) ? Qf : Kf;
    __bf16*      dst = (z < B_) ? Qb : Kb;
    const float scale = (z < B_) ? QSCALE : 1.0f;
    const int b = (z < B_) ? z : z - B_;
    const int n = blockIdx.y;
    const int t = threadIdx.x;
    const int d4 = (t & 15) * 4;
    const int s  = blockIdx.x * 16 + (t >> 4);

    const float4 v = *(const float4*)&src[(((size_t)b * S_ + s) * N_ + n) * D_ + d4];
    bf16x4 o;
    o[0] = (__bf16)(v.x * scale); o[1] = (__bf16)(v.y * scale);
    o[2] = (__bf16)(v.z * scale); o[3] = (__bf16)(v.w * scale);
    *(bf16x4*)&dst[(((size_t)b * N_ + n) * S_ + s) * D_ + d4] = o;
}

// ---------------------------------------------------------------------------
// Pre-pass 2: V [b,s,n,d] f32 -> [b,n,d,s] bf16 (d<->s transpose via LDS tile).
// ---------------------------------------------------------------------------
__global__ __launch_bounds__(256) void cvt_v_kernel(
    const float* __restrict__ V, __bf16* __restrict__ Vt)
{
    __shared__ __bf16 tile[64][68];  // +4 pad breaks bank aliasing
    const int s0 = blockIdx.x * 64;
    const int n  = blockIdx.y;
    const int b  = blockIdx.z;
    const int t  = threadIdx.x;

    {
        const int d4 = (t & 15) * 4;
        const int sr = t >> 4;
        #pragma unroll
        for (int r = 0; r < 4; ++r) {
            const int s = sr + r * 16;
            const float4 v = *(const float4*)&V[(((size_t)b * S_ + s0 + s) * N_ + n) * D_ + d4];
            tile[s][d4 + 0] = (__bf16)v.x;
            tile[s][d4 + 1] = (__bf16)v.y;
            tile[s][d4 + 2] = (__bf16)v.z;
            tile[s][d4 + 3] = (__bf16)v.w;
        }
    }
    __syncthreads();
    {
        const int s4 = (t & 15) * 4;
        const int dr = t >> 4;
        #pragma unroll
        for (int r = 0; r < 4; ++r) {
            const int d = dr + r * 16;
            bf16x4 o;
            o[0] = tile[s4 + 0][d];
            o[1] = tile[s4 + 1][d];
            o[2] = tile[s4 + 2][d];
            o[3] = tile[s4 + 3][d];
            *(bf16x4*)&Vt[(((size_t)b * N_ + n) * D_ + d) * S_ + s0 + s4] = o;
        }
    }
}

// ---------------------------------------------------------------------------
// Pass 1: Zr_t[b][k][q] = mask ? 1/sum_n exp2(s_n) : NaN   (TRANSPOSED store).
// Block = 256 thr = 4 waves; wave w: k-tile blockIdx.x*4+w, q-tile blockIdx.y.
// 16-head loop fully in registers (same C-layout per head -> VALU head-sum).
// Transpose via wave-private LDS 32x33 tile (conflict-free, no barriers).
// ---------------------------------------------------------------------------
__global__ __launch_bounds__(256, 3) void pass1_z_kernel(
    const __bf16* __restrict__ Qb, const __bf16* __restrict__ Kb,
    const int* __restrict__ M, float* __restrict__ Zrt)
{
    __shared__ float tile[4][32][33];   // 16.9 KB, per-wave

    const int tid  = threadIdx.x;
    const int wv   = tid >> 6;
    const int lane = tid & 63;
    const int lo   = lane & 31;
    const int hi   = lane >> 5;

    const int k0 = (blockIdx.x * 4 + wv) * TK;
    const int q0 = blockIdx.y * TQ;
    const int b  = blockIdx.z;

    const __bf16* Qp = Qb + (size_t)b * N_ * S_ * D_ + (size_t)(q0 + lo) * D_ + hi * 8;
    const __bf16* Kp = Kb + (size_t)b * N_ * S_ * D_ + (size_t)(k0 + lo) * D_ + hi * 8;

    f32x16 zsum = {};
    #pragma unroll
    for (int h = 0; h < N_; ++h) {
        const __bf16* Qh = Qp + (size_t)h * S_ * D_;
        const __bf16* Kh = Kp + (size_t)h * S_ * D_;
        bf16x8 qf[4], kf[4];
        #pragma unroll
        for (int ks = 0; ks < 4; ++ks) {
            qf[ks] = *(const bf16x8*)(Qh + ks * 16);
            kf[ks] = *(const bf16x8*)(Kh + ks * 16);
        }
        f32x16 s = {};
        #pragma unroll
        for (int ks = 0; ks < 4; ++ks)
            s = __builtin_amdgcn_mfma_f32_32x32x16_bf16(qf[ks], kf[ks], s, 0, 0, 0);
        // s = (q.k)/8 * log2(e) (scale folded into Q); single v_exp_f32 each
        #pragma unroll
        for (int r = 0; r < 16; ++r) zsum[r] += __builtin_amdgcn_exp2f(s[r]);
    }

    // mask + reciprocal, deposit in C-layout (q=row, k=lo)
    const size_t mb = (size_t)b * S_ * S_;
    #pragma unroll
    for (int r = 0; r < 16; ++r) {
        const int row = (r & 3) + 8 * (r >> 2) + 4 * hi;
        const int m = M[mb + (size_t)(q0 + row) * S_ + (k0 + lo)];
        // mask==0: ref softmax over all-(-inf) heads -> NaN weights
        tile[wv][row][lo] = m ? __builtin_amdgcn_rcpf(zsum[r]) : __builtin_nanf("");
    }
    // transposed read (stride-33 => conflict-free) + coalesced store to Zr_t[k][q]
    #pragma unroll
    for (int r = 0; r < 16; ++r) {
        const int kap = (r & 3) + 8 * (r >> 2) + 4 * hi;
        Zrt[mb + (size_t)(k0 + kap) * S_ + (q0 + lo)] = tile[wv][lo][kap];
    }
}

// ---------------------------------------------------------------------------
// Pass 2: out[b,n,q,:] = sum_k (exp2(s)*zr) V[k,:].
// Block = 256 thr = 4 waves, one (q-tile, head, b) per block; wave w sweeps
// k in [w*512, w*512+512). Swapped QK^T (S^T = mfma(K,Q)) puts each q-row
// lane-local; cvt_pk + permlane32_swap build PV A-frags in-register.
// NO LDS in the k-loop. End: one LDS combine of 4 k-partials, direct stores.
// ---------------------------------------------------------------------------
__global__ __launch_bounds__(256, 3) void pass2_av_kernel(
    const __bf16* __restrict__ Qb, const __bf16* __restrict__ Kb,
    const __bf16* __restrict__ Vt, const float* __restrict__ Zrt,
    float* __restrict__ O)
{
    __shared__ __align__(16) float obuf[4][TQ * D_];    // 32 KB, end combine

    const int tid  = threadIdx.x;
    const int wv   = tid >> 6;
    const int lane = tid & 63;
    const int lo   = lane & 31;
    const int hi   = lane >> 5;

    const int q0 = blockIdx.x * TQ;
    const int n  = blockIdx.y;
    const int b  = blockIdx.z;

    const __bf16* Qh = Qb + ((size_t)b * N_ + n) * S_ * D_;
    const __bf16* Kh = Kb + ((size_t)b * N_ + n) * S_ * D_;
    const __bf16* Vh = Vt + ((size_t)b * N_ + n) * D_ * S_;
    const float*  Zh = Zrt + (size_t)b * S_ * S_;

    // Q fragments (pre-scaled). Used as the B-operand of the swapped QK^T.
    bf16x8 qf[4];
    #pragma unroll
    for (int ks = 0; ks < 4; ++ks)
        qf[ks] = *(const bf16x8*)&Qh[(size_t)(q0 + lo) * D_ + ks * 16 + hi * 8];

    f32x16 o0 = {};  // out cols d =  0..31 (C layout)
    f32x16 o1 = {};  // out cols d = 32..63

    const int kb = wv * (S_ / 4);
    #pragma unroll 2
    for (int t = 0; t < 16; ++t) {
        const int k0 = kb + t * TK;

        // zr loads from TRANSPOSED Zr_t: per instr one row k, q=lo consecutive
        // -> coalesced. Issued early; L2-shared across the 16 head-blocks.
        float zr[16];
        #pragma unroll
        for (int r = 0; r < 16; ++r) {
            const int kap = (r & 3) + 8 * (r >> 2) + 4 * hi;
            zr[r] = Zh[(size_t)(k0 + kap) * S_ + q0 + lo];
        }

        // V B-frags (k = key, col = d = dt*32+lo)
        bf16x8 vf[2][2];
        #pragma unroll
        for (int kstep = 0; kstep < 2; ++kstep)
            #pragma unroll
            for (int dt = 0; dt < 2; ++dt)
                vf[kstep][dt] = *(const bf16x8*)&Vh[(size_t)(dt * 32 + lo) * S_
                                                   + k0 + kstep * 16 + hi * 8];

        // swapped QK^T: S^T[key=row][q=lo] -> lane (lo,hi) holds the scores of
        // q = q0+lo at keys kap(r,hi) = (r&3)+8*(r>>2)+4*hi (+k0)
        f32x16 s = {};
        #pragma unroll
        for (int ks = 0; ks < 4; ++ks) {
            bf16x8 kf = *(const bf16x8*)&Kh[(size_t)(k0 + lo) * D_ + ks * 16 + hi * 8];
            s = __builtin_amdgcn_mfma_f32_32x32x16_bf16(kf, qf[ks], s, 0, 0, 0);
        }

        // w = exp2(s) * zr  (single v_exp_f32 each; NaN propagates for mask==0)
        float w[16];
        #pragma unroll
        for (int r = 0; r < 16; ++r) w[r] = __builtin_amdgcn_exp2f(s[r]) * zr[r];

        // pack to bf16 + cross-half redistribute -> exact PV A-fragments.
        // kstep uses w[kstep*8 .. +7]  (keys kstep*16 .. +15 across both halves):
        //   d0=pk(w0,w1) d1=pk(w2,w3) d2=pk(w4,w5) d3=pk(w6,w7)
        //   swap(d0,d2), swap(d1,d3)  => dwords 0..3 of A-frag for BOTH halves.
        #pragma unroll
        for (int kstep = 0; kstep < 2; ++kstep) {
            const int e = kstep * 8;
            unsigned int d0 = cvt_pk_bf16(w[e + 0], w[e + 1]);
            unsigned int d1 = cvt_pk_bf16(w[e + 2], w[e + 3]);
            unsigned int d2 = cvt_pk_bf16(w[e + 4], w[e + 5]);
            unsigned int d3 = cvt_pk_bf16(w[e + 6], w[e + 7]);
            permlane_swap(d0, d2);
            permlane_swap(d1, d3);
            uint32x4 u; u[0] = d0; u[1] = d1; u[2] = d2; u[3] = d3;
            const bf16x8 pa = __builtin_bit_cast(bf16x8, u);
            o0 = __builtin_amdgcn_mfma_f32_32x32x16_bf16(pa, vf[kstep][0], o0, 0, 0, 0);
            o1 = __builtin_amdgcn_mfma_f32_32x32x16_bf16(pa, vf[kstep][1], o1, 0, 0, 0);
        }
    }

    // k-split combine: each wave deposits its partial tile, one barrier,
    // then 256 threads tree-sum 4 partials and store coalesced f32x4.
    #pragma unroll
    for (int r = 0; r < 16; ++r) {
        const int row = (r & 3) + 8 * (r >> 2) + 4 * hi;
        obuf[wv][row * D_ + lo]      = o0[r];
        obuf[wv][row * D_ + 32 + lo] = o1[r];
    }
    __syncthreads();

    {
        const int e0 = tid * 8;          // 8 consecutive output f32 per thread
        float a[8] = {0, 0, 0, 0, 0, 0, 0, 0};
        #pragma unroll
        for (int w = 0; w < 4; ++w) {
            const float4 x = *(const float4*)&obuf[w][e0];
            const float4 y = *(const float4*)&obuf[w][e0 + 4];
            a[0] += x.x; a[1] += x.y; a[2] += x.z; a[3] += x.w;
            a[4] += y.x; a[5] += y.y; a[6] += y.z; a[7] += y.w;
        }
        const int q = e0 >> 6;
        const int d = e0 & 63;
        float* dst = &O[(((size_t)b * N_ + n) * S_ + q0 + q) * (size_t)D_ + d];
        *(float4*)dst       = make_float4(a[0], a[1], a[2], a[3]);
        *(float4*)(dst + 4) = make_float4(a[4], a[5], a[6], a[7]);
    }
}

// ---------------------------------------------------------------------------
// Fallback (fp32 inputs): used only if ws is too small.
// ---------------------------------------------------------------------------
__global__ __launch_bounds__(1024) void sdpa_headsm_kernel(
    const float* __restrict__ Q, const float* __restrict__ K,
    const float* __restrict__ V, const int* __restrict__ M,
    float* __restrict__ O)
{
    __shared__ __align__(16) __bf16 pbuf[N_][TQ][40];

    const int tid  = threadIdx.x;
    const int n    = tid >> 6;
    const int lane = tid & 63;
    const int lo   = lane & 31;
    const int hi   = lane >> 5;

    const int q0 = blockIdx.x * TQ;
    const int b  = blockIdx.y;
    const int kz = blockIdx.z;
    const int FITERS = S_ / TK / 4;

    bf16x8 qf[4];
    {
        const float* qrow = Q + (((size_t)b * S_ + (size_t)(q0 + lo)) * N_ + n) * D_;
        #pragma unroll
        for (int ks = 0; ks < 4; ++ks) {
            const float* p = qrow + ks * 16 + hi * 8;
            float4 a0 = *(const float4*)(p);
            float4 a1 = *(const float4*)(p + 4);
            bf16x8 f;
            f[0] = (__bf16)a0.x; f[1] = (__bf16)a0.y;
            f[2] = (__bf16)a0.z; f[3] = (__bf16)a0.w;
            f[4] = (__bf16)a1.x; f[5] = (__bf16)a1.y;
            f[6] = (__bf16)a1.z; f[7] = (__bf16)a1.w;
            qf[ks] = f;
        }
    }

    f32x16 o0 = {};
    f32x16 o1 = {};

    for (int it = 0; it < FITERS; ++it) {
        const int k0 = (kz * FITERS + it) * TK;

        f32x16 s = {};
        #pragma unroll
        for (int ks = 0; ks < 4; ++ks) {
            const float* krow = K + (((size_t)b * S_ + (size_t)(k0 + lo)) * N_ + n) * D_
                                  + ks * 16 + hi * 8;
            float4 a0 = *(const float4*)(krow);
            float4 a1 = *(const float4*)(krow + 4);
            bf16x8 f;
            f[0] = (__bf16)a0.x; f[1] = (__bf16)a0.y;
            f[2] = (__bf16)a0.z; f[3] = (__bf16)a0.w;
            f[4] = (__bf16)a1.x; f[5] = (__bf16)a1.y;
            f[6] = (__bf16)a1.z; f[7] = (__bf16)a1.w;
            s = __builtin_amdgcn_mfma_f32_32x32x16_bf16(qf[ks], f, s, 0, 0, 0);
        }

        bf16x8 vf[2][2];
        #pragma unroll
        for (int kstep = 0; kstep < 2; ++kstep) {
            #pragma unroll
            for (int dt = 0; dt < 2; ++dt) {
                bf16x8 f;
                #pragma unroll
                for (int j = 0; j < 8; ++j) {
                    const int key = k0 + kstep * 16 + hi * 8 + j;
                    f[j] = (__bf16)V[(((size_t)b * S_ + key) * N_ + n) * D_ + dt * 32 + lo];
                }
                vf[kstep][dt] = f;
            }
        }

        #pragma unroll
        for (int r = 0; r < 16; ++r) {
            const int row = (r & 3) + 8 * (r >> 2) + 4 * hi;
            pbuf[n][row][lo] = (__bf16)__builtin_amdgcn_exp2f(s[r] * QSCALE);
        }

        __syncthreads();

        {
            const int tq = tid >> 5;
            const int tk = tid & 31;
            const int m = M[(size_t)b * S_ * S_ + (size_t)(q0 + tq) * S_ + (k0 + tk)];
            float pv[16];
            float sum = 0.f;
            #pragma unroll
            for (int j = 0; j < 16; ++j) { pv[j] = (float)pbuf[j][tq][tk]; sum += pv[j]; }
            const float rd = m ? (1.0f / sum) : __builtin_nanf("");
            #pragma unroll
            for (int j = 0; j < 16; ++j) pbuf[j][tq][tk] = (__bf16)(pv[j] * rd);
        }

        __syncthreads();

        #pragma unroll
        for (int kstep = 0; kstep < 2; ++kstep) {
            bf16x8 wf = *(const bf16x8*)&pbuf[n][lo][kstep * 16 + hi * 8];
            o0 = __builtin_amdgcn_mfma_f32_32x32x16_bf16(wf, vf[kstep][0], o0, 0, 0, 0);
            o1 = __builtin_amdgcn_mfma_f32_32x32x16_bf16(wf, vf[kstep][1], o1, 0, 0, 0);
        }

        __syncthreads();
    }

    #pragma unroll
    for (int r = 0; r < 16; ++r) {
        const int row = (r & 3) + 8 * (r >> 2) + 4 * hi;
        const size_t base = (((size_t)b * N_ + n) * S_ + (q0 + row)) * (size_t)D_;
        atomicAdd(&O[base + lo],      o0[r]);
        atomicAdd(&O[base + 32 + lo], o1[r]);
    }
}

extern "C" void kernel_launch(void* const* d_in, const int* in_sizes, int n_in,
                              void* d_out, int out_size, void* d_ws, size_t ws_size,
                              hipStream_t stream) {
    const float* Q = (const float*)d_in[0];
    const float* K = (const float*)d_in[1];
    const float* V = (const float*)d_in[2];
    const int*   M = (const int*)d_in[3];
    float* O = (float*)d_out;

    const size_t per  = (size_t)B_ * N_ * S_ * D_;         // 4,194,304 elements
    const size_t zcnt = (size_t)B_ * S_ * S_;              // 8,388,608 elements
    const size_t need = 3 * per * sizeof(__bf16) + zcnt * sizeof(float);  // 56 MB

    if (ws_size >= need) {
        __bf16* Qb = (__bf16*)d_ws;
        __bf16* Kb = Qb + per;
        __bf16* Vt = Kb + per;
        float*  Zrt = (float*)(Vt + per);
        cvt_qk_kernel<<<dim3(S_ / 16, N_, B_ * 2), dim3(256), 0, stream>>>(Q, K, Qb, Kb);
        cvt_v_kernel<<<dim3(S_ / 64, N_, B_), dim3(256), 0, stream>>>(V, Vt);
        pass1_z_kernel<<<dim3(S_ / TK / 4, S_ / TQ, B_), dim3(256), 0, stream>>>(Qb, Kb, M, Zrt);
        pass2_av_kernel<<<dim3(S_ / TQ, N_, B_), dim3(256), 0, stream>>>(Qb, Kb, Vt, Zrt, O);
    } else {
        hipMemsetAsync(d_out, 0, (size_t)out_size * sizeof(float), stream);
        sdpa_headsm_kernel<<<dim3(S_ / TQ, B_, 4), dim3(1024), 0, stream>>>(Q, K, V, M, O);
    }
}

// Round 4
// 242.166 us; speedup vs baseline: 1.6271x; 1.6271x over previous
//
#include <hip/hip_runtime.h>
#include <hip/hip_bf16.h>

// Head-axis-softmax SDPA, B=2 S=2048 N=16 D=64, fp32 in/out.
// softmax over HEADS (n) -> local per (b,q,k).
//
// R8: fragment-major packed layouts. R7 post-mortem: all structures floor at
// ~150-215us with every pipe <20% busy; the invariant is fragment loads at
// 128B lane stride (32 cache lines / wave-instr instead of 8) -> L1/TA
// transaction occupancy is the hidden serializer. Fix: pre-passes repack
// Q,K,V into the exact per-lane MFMA fragment order:
//   QP,KP[b][n][s-tile][ks][lane][8]      (tile = 32 rows x 64 k -> 4KB)
//   VP   [b][n][k-tile][kstep][dt][lane][8]
// so every hot-loop load is lane-contiguous 1KB (coalesced), with
// loop-invariant vaddr. Math identical to R7 (passed): two-pass Z
// factorization, swapped QK^T + cvt_pk/permlane in-register PV A-frags,
// v_exp_f32 via __builtin_amdgcn_exp2f, transposed Zrt.

#define B_ 2
#define S_ 2048
#define N_ 16
#define D_ 64
#define TQ 32
#define TK 32
#define NT 64   // S_/32 tiles per head

typedef __bf16 bf16x4 __attribute__((ext_vector_type(4)));
typedef __bf16 bf16x8 __attribute__((ext_vector_type(8)));
typedef float  f32x16 __attribute__((ext_vector_type(16)));
typedef unsigned int uint32x4 __attribute__((ext_vector_type(4)));

// scale folded into Q at conversion: 1/sqrt(64) * log2(e)
#define QSCALE 0.18033688011112042f

static __device__ __forceinline__ unsigned int cvt_pk_bf16(float a, float b) {
    // dst low16 = bf16(a), high16 = bf16(b)
    unsigned int r;
    asm("v_cvt_pk_bf16_f32 %0, %1, %2" : "=v"(r) : "v"(a), "v"(b));
    return r;
}
static __device__ __forceinline__ void permlane_swap(unsigned int& a, unsigned int& b) {
    // exchanges a's lanes[32:63] with b's lanes[0:31]
    asm("v_permlane32_swap_b32 %0, %1" : "+v"(a), "+v"(b));
}

// ---------------------------------------------------------------------------
// Pre-pass 1: Q,K [b,s,n,d] f32 -> fragment-major packed bf16.
// Block = one (s-tile, n, z). Thread t: ks=t>>6, lane=t&63 -> reads 8 f32
// from source row (st*32+lo), writes 16B at dst tile offset t*16 (coalesced).
// Q pre-scaled by QSCALE.
// ---------------------------------------------------------------------------
__global__ __launch_bounds__(256) void cvt_qk_pack_kernel(
    const float* __restrict__ Qf, const float* __restrict__ Kf,
    __bf16* __restrict__ QP, __bf16* __restrict__ KP)
{
    const int z = blockIdx.z;                  // 0..2B-1: first B -> Q, rest -> K
    const float* src = (z < B_) ? Qf : Kf;
    __bf16*      dst = (z < B_) ? QP : KP;
    const float scale = (z < B_) ? QSCALE : 1.0f;
    const int b  = (z < B_) ? z : z - B_;
    const int n  = blockIdx.y;
    const int st = blockIdx.x;                 // s-tile 0..63
    const int t  = threadIdx.x;
    const int ks   = t >> 6;
    const int lane = t & 63;
    const int lo   = lane & 31;
    const int hi   = lane >> 5;

    const float* p = &src[(((size_t)b * S_ + st * 32 + lo) * N_ + n) * D_ + ks * 16 + hi * 8];
    const float4 a0 = *(const float4*)p;
    const float4 a1 = *(const float4*)(p + 4);
    bf16x8 o;
    o[0] = (__bf16)(a0.x * scale); o[1] = (__bf16)(a0.y * scale);
    o[2] = (__bf16)(a0.z * scale); o[3] = (__bf16)(a0.w * scale);
    o[4] = (__bf16)(a1.x * scale); o[5] = (__bf16)(a1.y * scale);
    o[6] = (__bf16)(a1.z * scale); o[7] = (__bf16)(a1.w * scale);
    *(bf16x8*)&dst[(((size_t)b * N_ + n) * NT + st) * 2048 + (size_t)t * 8] = o;
}

// ---------------------------------------------------------------------------
// Pre-pass 2: V [b,s,n,d] f32 -> fragment-major packed bf16 (via LDS tile).
// Block covers 64 s-rows (= 2 k-tiles) for one (b,n).
// Phase 1: coalesced f32 reads -> tile[s][d]. Phase 2: thread t emits the
// packed group (kstep=t>>7, dt=(t>>6)&1, lane=t&63) for each sub-tile;
// writes are 16B at tile offset t*16 (coalesced).
// ---------------------------------------------------------------------------
__global__ __launch_bounds__(256) void cvt_v_pack_kernel(
    const float* __restrict__ V, __bf16* __restrict__ VP)
{
    __shared__ __bf16 tile[64][68];  // +4 pad breaks bank aliasing
    const int s0 = blockIdx.x * 64;
    const int n  = blockIdx.y;
    const int b  = blockIdx.z;
    const int t  = threadIdx.x;

    {
        const int d4 = (t & 15) * 4;
        const int sr = t >> 4;
        #pragma unroll
        for (int r = 0; r < 4; ++r) {
            const int s = sr + r * 16;
            const float4 v = *(const float4*)&V[(((size_t)b * S_ + s0 + s) * N_ + n) * D_ + d4];
            tile[s][d4 + 0] = (__bf16)v.x;
            tile[s][d4 + 1] = (__bf16)v.y;
            tile[s][d4 + 2] = (__bf16)v.z;
            tile[s][d4 + 3] = (__bf16)v.w;
        }
    }
    __syncthreads();
    {
        const int kstep = t >> 7;        // 0..1
        const int dt    = (t >> 6) & 1;
        const int lane  = t & 63;
        const int lo    = lane & 31;
        const int hi    = lane >> 5;
        #pragma unroll
        for (int kt_sub = 0; kt_sub < 2; ++kt_sub) {
            bf16x8 o;
            #pragma unroll
            for (int j = 0; j < 8; ++j)
                o[j] = tile[kt_sub * 32 + kstep * 16 + hi * 8 + j][dt * 32 + lo];
            const size_t kt = (size_t)(blockIdx.x * 2 + kt_sub);
            *(bf16x8*)&VP[(((size_t)b * N_ + n) * NT + kt) * 2048 + (size_t)t * 8] = o;
        }
    }
}

// ---------------------------------------------------------------------------
// Pass 1: Zr_t[b][k][q] = mask ? 1/sum_n exp2(s_n) : NaN   (TRANSPOSED store).
// Block = 256 thr = 4 waves; wave w: k-tile blockIdx.x*4+w, q-tile blockIdx.y.
// Head loop in registers (same C-layout per head -> VALU head-sum).
// All fragment loads lane-contiguous from packed layout.
// ---------------------------------------------------------------------------
__global__ __launch_bounds__(256, 4) void pass1_z_kernel(
    const __bf16* __restrict__ QP, const __bf16* __restrict__ KP,
    const int* __restrict__ M, float* __restrict__ Zrt)
{
    __shared__ float tile[4][32][33];   // 16.9 KB, per-wave

    const int tid  = threadIdx.x;
    const int wv   = tid >> 6;
    const int lane = tid & 63;
    const int lo   = lane & 31;
    const int hi   = lane >> 5;

    const int kt = blockIdx.x * 4 + wv;
    const int qt = blockIdx.y;
    const int b  = blockIdx.z;
    const int k0 = kt * TK;
    const int q0 = qt * TQ;

    const __bf16* Qp = QP + ((size_t)b * N_ * NT + qt) * 2048 + (size_t)lane * 8;
    const __bf16* Kp = KP + ((size_t)b * N_ * NT + kt) * 2048 + (size_t)lane * 8;

    f32x16 zsum = {};
    #pragma unroll 4
    for (int h = 0; h < N_; ++h) {
        const __bf16* Qh = Qp + (size_t)h * NT * 2048;
        const __bf16* Kh = Kp + (size_t)h * NT * 2048;
        bf16x8 qf[4], kf[4];
        #pragma unroll
        for (int ks = 0; ks < 4; ++ks) {
            qf[ks] = *(const bf16x8*)(Qh + ks * 512);
            kf[ks] = *(const bf16x8*)(Kh + ks * 512);
        }
        f32x16 s = {};
        #pragma unroll
        for (int ks = 0; ks < 4; ++ks)
            s = __builtin_amdgcn_mfma_f32_32x32x16_bf16(qf[ks], kf[ks], s, 0, 0, 0);
        // s = (q.k)/8 * log2(e) (scale folded into Q); single v_exp_f32 each
        #pragma unroll
        for (int r = 0; r < 16; ++r) zsum[r] += __builtin_amdgcn_exp2f(s[r]);
    }

    // mask + reciprocal, deposit in C-layout (q=row, k=lo)
    const size_t mb = (size_t)b * S_ * S_;
    #pragma unroll
    for (int r = 0; r < 16; ++r) {
        const int row = (r & 3) + 8 * (r >> 2) + 4 * hi;
        const int m = M[mb + (size_t)(q0 + row) * S_ + (k0 + lo)];
        // mask==0: ref softmax over all-(-inf) heads -> NaN weights
        tile[wv][row][lo] = m ? __builtin_amdgcn_rcpf(zsum[r]) : __builtin_nanf("");
    }
    // transposed read (stride-33 => conflict-free) + coalesced store to Zr_t[k][q]
    #pragma unroll
    for (int r = 0; r < 16; ++r) {
        const int kap = (r & 3) + 8 * (r >> 2) + 4 * hi;
        Zrt[mb + (size_t)(k0 + kap) * S_ + (q0 + lo)] = tile[wv][lo][kap];
    }
}

// ---------------------------------------------------------------------------
// Pass 2: out[b,n,q,:] = sum_k (exp2(s)*zr) V[k,:].
// Block = 256 thr = 4 waves, one (q-tile, head, b) per block; wave w sweeps
// k-tiles [w*16, w*16+16). Swapped QK^T (S^T = mfma(K,Q)) puts each q-row
// lane-local; cvt_pk + permlane32_swap build PV A-frags in-register.
// All fragment loads lane-contiguous. End: chunked (2x16-row) LDS combine
// of 4 k-partials, direct coalesced stores.
// ---------------------------------------------------------------------------
__global__ __launch_bounds__(256, 4) void pass2_av_kernel(
    const __bf16* __restrict__ QP, const __bf16* __restrict__ KP,
    const __bf16* __restrict__ VP, const float* __restrict__ Zrt,
    float* __restrict__ O)
{
    __shared__ __align__(16) float obuf[4][16 * D_];    // 16 KB, end combine

    const int tid  = threadIdx.x;
    const int wv   = tid >> 6;
    const int lane = tid & 63;
    const int lo   = lane & 31;
    const int hi   = lane >> 5;

    const int qt = blockIdx.x;
    const int n  = blockIdx.y;
    const int b  = blockIdx.z;
    const int q0 = qt * TQ;

    const __bf16* Qh = QP + (((size_t)b * N_ + n) * NT + qt) * 2048 + (size_t)lane * 8;
    const __bf16* Kh = KP + (((size_t)b * N_ + n) * NT) * 2048 + (size_t)lane * 8;
    const __bf16* Vh = VP + (((size_t)b * N_ + n) * NT) * 2048 + (size_t)lane * 8;
    const float*  Zh = Zrt + (size_t)b * S_ * S_;

    // Q fragments (pre-scaled). B-operand of the swapped QK^T.
    bf16x8 qf[4];
    #pragma unroll
    for (int ks = 0; ks < 4; ++ks)
        qf[ks] = *(const bf16x8*)(Qh + ks * 512);

    f32x16 o0 = {};  // out cols d =  0..31 (C layout)
    f32x16 o1 = {};  // out cols d = 32..63

    #pragma unroll 2
    for (int t = 0; t < 16; ++t) {
        const int kt = wv * 16 + t;
        const int k0 = kt * TK;
        const __bf16* Kt = Kh + (size_t)kt * 2048;
        const __bf16* Vt = Vh + (size_t)kt * 2048;

        // zr loads from TRANSPOSED Zr_t: q=lo consecutive -> coalesced.
        float zr[16];
        #pragma unroll
        for (int r = 0; r < 16; ++r) {
            const int kap = (r & 3) + 8 * (r >> 2) + 4 * hi;
            zr[r] = Zh[(size_t)(k0 + kap) * S_ + q0 + lo];
        }

        // V B-frags: lane-contiguous 1KB each
        bf16x8 vf[2][2];
        #pragma unroll
        for (int kstep = 0; kstep < 2; ++kstep)
            #pragma unroll
            for (int dt = 0; dt < 2; ++dt)
                vf[kstep][dt] = *(const bf16x8*)(Vt + (kstep * 2 + dt) * 512);

        // swapped QK^T: S^T[key=row][q=lo]; lane (lo,hi) holds scores of
        // q = q0+lo at keys kap(r,hi) = (r&3)+8*(r>>2)+4*hi (+k0)
        f32x16 s = {};
        #pragma unroll
        for (int ks = 0; ks < 4; ++ks) {
            bf16x8 kf = *(const bf16x8*)(Kt + ks * 512);
            s = __builtin_amdgcn_mfma_f32_32x32x16_bf16(kf, qf[ks], s, 0, 0, 0);
        }

        // w = exp2(s) * zr  (single v_exp_f32; NaN propagates for mask==0)
        float w[16];
        #pragma unroll
        for (int r = 0; r < 16; ++r) w[r] = __builtin_amdgcn_exp2f(s[r]) * zr[r];

        // pack to bf16 + cross-half redistribute -> exact PV A-fragments.
        #pragma unroll
        for (int kstep = 0; kstep < 2; ++kstep) {
            const int e = kstep * 8;
            unsigned int d0 = cvt_pk_bf16(w[e + 0], w[e + 1]);
            unsigned int d1 = cvt_pk_bf16(w[e + 2], w[e + 3]);
            unsigned int d2 = cvt_pk_bf16(w[e + 4], w[e + 5]);
            unsigned int d3 = cvt_pk_bf16(w[e + 6], w[e + 7]);
            permlane_swap(d0, d2);
            permlane_swap(d1, d3);
            uint32x4 u; u[0] = d0; u[1] = d1; u[2] = d2; u[3] = d3;
            const bf16x8 pa = __builtin_bit_cast(bf16x8, u);
            o0 = __builtin_amdgcn_mfma_f32_32x32x16_bf16(pa, vf[kstep][0], o0, 0, 0, 0);
            o1 = __builtin_amdgcn_mfma_f32_32x32x16_bf16(pa, vf[kstep][1], o1, 0, 0, 0);
        }
    }

    // k-split combine, chunked 2 x 16 rows (obuf 16KB). r<8 -> rows 0..15.
    #pragma unroll
    for (int half = 0; half < 2; ++half) {
        if (half) __syncthreads();   // protect obuf reuse
        #pragma unroll
        for (int r8 = 0; r8 < 8; ++r8) {
            const int r  = half * 8 + r8;
            const int lr = (r8 & 3) + 8 * (r8 >> 2) + 4 * hi;  // row - 16*half
            obuf[wv][lr * D_ + lo]      = o0[r];
            obuf[wv][lr * D_ + 32 + lo] = o1[r];
        }
        __syncthreads();
        const int e0 = tid * 4;          // 1024 f32 per half / 256 thr
        float a0 = 0.f, a1 = 0.f, a2 = 0.f, a3 = 0.f;
        #pragma unroll
        for (int w = 0; w < 4; ++w) {
            const float4 x = *(const float4*)&obuf[w][e0];
            a0 += x.x; a1 += x.y; a2 += x.z; a3 += x.w;
        }
        const int q = half * 16 + (e0 >> 6);
        const int d = e0 & 63;
        *(float4*)&O[(((size_t)b * N_ + n) * S_ + q0 + q) * (size_t)D_ + d]
            = make_float4(a0, a1, a2, a3);
    }
}

// ---------------------------------------------------------------------------
// Fallback (fp32 inputs): used only if ws is too small.
// ---------------------------------------------------------------------------
__global__ __launch_bounds__(1024) void sdpa_headsm_kernel(
    const float* __restrict__ Q, const float* __restrict__ K,
    const float* __restrict__ V, const int* __restrict__ M,
    float* __restrict__ O)
{
    __shared__ __align__(16) __bf16 pbuf[N_][TQ][40];

    const int tid  = threadIdx.x;
    const int n    = tid >> 6;
    const int lane = tid & 63;
    const int lo   = lane & 31;
    const int hi   = lane >> 5;

    const int q0 = blockIdx.x * TQ;
    const int b  = blockIdx.y;
    const int kz = blockIdx.z;
    const int FITERS = S_ / TK / 4;

    bf16x8 qf[4];
    {
        const float* qrow = Q + (((size_t)b * S_ + (size_t)(q0 + lo)) * N_ + n) * D_;
        #pragma unroll
        for (int ks = 0; ks < 4; ++ks) {
            const float* p = qrow + ks * 16 + hi * 8;
            float4 a0 = *(const float4*)(p);
            float4 a1 = *(const float4*)(p + 4);
            bf16x8 f;
            f[0] = (__bf16)a0.x; f[1] = (__bf16)a0.y;
            f[2] = (__bf16)a0.z; f[3] = (__bf16)a0.w;
            f[4] = (__bf16)a1.x; f[5] = (__bf16)a1.y;
            f[6] = (__bf16)a1.z; f[7] = (__bf16)a1.w;
            qf[ks] = f;
        }
    }

    f32x16 o0 = {};
    f32x16 o1 = {};

    for (int it = 0; it < FITERS; ++it) {
        const int k0 = (kz * FITERS + it) * TK;

        f32x16 s = {};
        #pragma unroll
        for (int ks = 0; ks < 4; ++ks) {
            const float* krow = K + (((size_t)b * S_ + (size_t)(k0 + lo)) * N_ + n) * D_
                                  + ks * 16 + hi * 8;
            float4 a0 = *(const float4*)(krow);
            float4 a1 = *(const float4*)(krow + 4);
            bf16x8 f;
            f[0] = (__bf16)a0.x; f[1] = (__bf16)a0.y;
            f[2] = (__bf16)a0.z; f[3] = (__bf16)a0.w;
            f[4] = (__bf16)a1.x; f[5] = (__bf16)a1.y;
            f[6] = (__bf16)a1.z; f[7] = (__bf16)a1.w;
            s = __builtin_amdgcn_mfma_f32_32x32x16_bf16(qf[ks], f, s, 0, 0, 0);
        }

        bf16x8 vf[2][2];
        #pragma unroll
        for (int kstep = 0; kstep < 2; ++kstep) {
            #pragma unroll
            for (int dt = 0; dt < 2; ++dt) {
                bf16x8 f;
                #pragma unroll
                for (int j = 0; j < 8; ++j) {
                    const int key = k0 + kstep * 16 + hi * 8 + j;
                    f[j] = (__bf16)V[(((size_t)b * S_ + key) * N_ + n) * D_ + dt * 32 + lo];
                }
                vf[kstep][dt] = f;
            }
        }

        #pragma unroll
        for (int r = 0; r < 16; ++r) {
            const int row = (r & 3) + 8 * (r >> 2) + 4 * hi;
            pbuf[n][row][lo] = (__bf16)__builtin_amdgcn_exp2f(s[r] * QSCALE);
        }

        __syncthreads();

        {
            const int tq = tid >> 5;
            const int tk = tid & 31;
            const int m = M[(size_t)b * S_ * S_ + (size_t)(q0 + tq) * S_ + (k0 + tk)];
            float pv[16];
            float sum = 0.f;
            #pragma unroll
            for (int j = 0; j < 16; ++j) { pv[j] = (float)pbuf[j][tq][tk]; sum += pv[j]; }
            const float rd = m ? (1.0f / sum) : __builtin_nanf("");
            #pragma unroll
            for (int j = 0; j < 16; ++j) pbuf[j][tq][tk] = (__bf16)(pv[j] * rd);
        }

        __syncthreads();

        #pragma unroll
        for (int kstep = 0; kstep < 2; ++kstep) {
            bf16x8 wf = *(const bf16x8*)&pbuf[n][lo][kstep * 16 + hi * 8];
            o0 = __builtin_amdgcn_mfma_f32_32x32x16_bf16(wf, vf[kstep][0], o0, 0, 0, 0);
            o1 = __builtin_amdgcn_mfma_f32_32x32x16_bf16(wf, vf[kstep][1], o1, 0, 0, 0);
        }

        __syncthreads();
    }

    #pragma unroll
    for (int r = 0; r < 16; ++r) {
        const int row = (r & 3) + 8 * (r >> 2) + 4 * hi;
        const size_t base = (((size_t)b * N_ + n) * S_ + (q0 + row)) * (size_t)D_;
        atomicAdd(&O[base + lo],      o0[r]);
        atomicAdd(&O[base + 32 + lo], o1[r]);
    }
}

extern "C" void kernel_launch(void* const* d_in, const int* in_sizes, int n_in,
                              void* d_out, int out_size, void* d_ws, size_t ws_size,
                              hipStream_t stream) {
    const float* Q = (const float*)d_in[0];
    const float* K = (const float*)d_in[1];
    const float* V = (const float*)d_in[2];
    const int*   M = (const int*)d_in[3];
    float* O = (float*)d_out;

    const size_t per  = (size_t)B_ * N_ * NT * 2048;       // 4,194,304 elements
    const size_t zcnt = (size_t)B_ * S_ * S_;              // 8,388,608 elements
    const size_t need = 3 * per * sizeof(__bf16) + zcnt * sizeof(float);  // 56 MB

    if (ws_size >= need) {
        __bf16* QP = (__bf16*)d_ws;
        __bf16* KP = QP + per;
        __bf16* VP = KP + per;
        float*  Zrt = (float*)(VP + per);
        cvt_qk_pack_kernel<<<dim3(NT, N_, B_ * 2), dim3(256), 0, stream>>>(Q, K, QP, KP);
        cvt_v_pack_kernel<<<dim3(S_ / 64, N_, B_), dim3(256), 0, stream>>>(V, VP);
        pass1_z_kernel<<<dim3(S_ / TK / 4, S_ / TQ, B_), dim3(256), 0, stream>>>(QP, KP, M, Zrt);
        pass2_av_kernel<<<dim3(S_ / TQ, N_, B_), dim3(256), 0, stream>>>(QP, KP, VP, Zrt, O);
    } else {
        hipMemsetAsync(d_out, 0, (size_t)out_size * sizeof(float), stream);
        sdpa_headsm_kernel<<<dim3(S_ / TQ, B_, 4), dim3(1024), 0, stream>>>(Q, K, V, M, O);
    }
}

// Round 5
// 220.434 us; speedup vs baseline: 1.7875x; 1.0986x over previous
//
#include <hip/hip_runtime.h>
#include <hip/hip_bf16.h>

// Head-axis-softmax SDPA, B=2 S=2048 N=16 D=64, fp32 in/out.
// softmax over HEADS (n) -> local per (b,q,k).
//
// R9: packed-fragment Zr + swapped-QK pass1.
// R8 confirmed the transaction-occupancy model (coalesced frag loads:
// pass2 159.6->83.9us). Remaining: pass2's 16 scattered zr dwords +
// addr VALU per tile; pass1's LDS transpose + scatter stores + 64x Q/K
// L2 re-reads. Changes:
//   - Zrt fragment-major [b][kt][qt][c][lane][4] f32: pass1 computes
//     SWAPPED QK^T (mfma(K,Q)) so its C-layout IS pass2's fragment
//     layout -> direct 4x float4 coalesced stores, no LDS transpose;
//     pass2 zr = 4x b128 loads with imm offsets.
//   - Mask: coalesced 32x64 AND-reduce + __all -> wave-uniform fast path
//     (mask all-ones in this problem); rare scattered slow path kept.
//   - pass1: 2 k-tiles per wave share Q frags (halves Q L2 traffic).

#define B_ 2
#define S_ 2048
#define N_ 16
#define D_ 64
#define TQ 32
#define TK 32
#define NT 64   // S_/32 tiles per head

typedef __bf16 bf16x4 __attribute__((ext_vector_type(4)));
typedef __bf16 bf16x8 __attribute__((ext_vector_type(8)));
typedef float  f32x16 __attribute__((ext_vector_type(16)));
typedef unsigned int uint32x4 __attribute__((ext_vector_type(4)));

// scale folded into Q at conversion: 1/sqrt(64) * log2(e)
#define QSCALE 0.18033688011112042f

static __device__ __forceinline__ unsigned int cvt_pk_bf16(float a, float b) {
    // dst low16 = bf16(a), high16 = bf16(b)
    unsigned int r;
    asm("v_cvt_pk_bf16_f32 %0, %1, %2" : "=v"(r) : "v"(a), "v"(b));
    return r;
}
static __device__ __forceinline__ void permlane_swap(unsigned int& a, unsigned int& b) {
    // exchanges a's lanes[32:63] with b's lanes[0:31]
    asm("v_permlane32_swap_b32 %0, %1" : "+v"(a), "+v"(b));
}

// ---------------------------------------------------------------------------
// Pre-pass 1: Q,K [b,s,n,d] f32 -> fragment-major packed bf16.
// QP,KP[b][n][s-tile][ks][lane][8]; Q pre-scaled by QSCALE.
// ---------------------------------------------------------------------------
__global__ __launch_bounds__(256) void cvt_qk_pack_kernel(
    const float* __restrict__ Qf, const float* __restrict__ Kf,
    __bf16* __restrict__ QP, __bf16* __restrict__ KP)
{
    const int z = blockIdx.z;                  // 0..2B-1: first B -> Q, rest -> K
    const float* src = (z < B_) ? Qf : Kf;
    __bf16*      dst = (z < B_) ? QP : KP;
    const float scale = (z < B_) ? QSCALE : 1.0f;
    const int b  = (z < B_) ? z : z - B_;
    const int n  = blockIdx.y;
    const int st = blockIdx.x;                 // s-tile 0..63
    const int t  = threadIdx.x;
    const int ks   = t >> 6;
    const int lane = t & 63;
    const int lo   = lane & 31;
    const int hi   = lane >> 5;

    const float* p = &src[(((size_t)b * S_ + st * 32 + lo) * N_ + n) * D_ + ks * 16 + hi * 8];
    const float4 a0 = *(const float4*)p;
    const float4 a1 = *(const float4*)(p + 4);
    bf16x8 o;
    o[0] = (__bf16)(a0.x * scale); o[1] = (__bf16)(a0.y * scale);
    o[2] = (__bf16)(a0.z * scale); o[3] = (__bf16)(a0.w * scale);
    o[4] = (__bf16)(a1.x * scale); o[5] = (__bf16)(a1.y * scale);
    o[6] = (__bf16)(a1.z * scale); o[7] = (__bf16)(a1.w * scale);
    *(bf16x8*)&dst[(((size_t)b * N_ + n) * NT + st) * 2048 + (size_t)t * 8] = o;
}

// ---------------------------------------------------------------------------
// Pre-pass 2: V [b,s,n,d] f32 -> fragment-major packed bf16 (via LDS tile).
// VP[b][n][k-tile][kstep][dt][lane][8].
// ---------------------------------------------------------------------------
__global__ __launch_bounds__(256) void cvt_v_pack_kernel(
    const float* __restrict__ V, __bf16* __restrict__ VP)
{
    __shared__ __bf16 tile[64][68];  // +4 pad breaks bank aliasing
    const int s0 = blockIdx.x * 64;
    const int n  = blockIdx.y;
    const int b  = blockIdx.z;
    const int t  = threadIdx.x;

    {
        const int d4 = (t & 15) * 4;
        const int sr = t >> 4;
        #pragma unroll
        for (int r = 0; r < 4; ++r) {
            const int s = sr + r * 16;
            const float4 v = *(const float4*)&V[(((size_t)b * S_ + s0 + s) * N_ + n) * D_ + d4];
            tile[s][d4 + 0] = (__bf16)v.x;
            tile[s][d4 + 1] = (__bf16)v.y;
            tile[s][d4 + 2] = (__bf16)v.z;
            tile[s][d4 + 3] = (__bf16)v.w;
        }
    }
    __syncthreads();
    {
        const int kstep = t >> 7;        // 0..1
        const int dt    = (t >> 6) & 1;
        const int lane  = t & 63;
        const int lo    = lane & 31;
        const int hi    = lane >> 5;
        #pragma unroll
        for (int kt_sub = 0; kt_sub < 2; ++kt_sub) {
            bf16x8 o;
            #pragma unroll
            for (int j = 0; j < 8; ++j)
                o[j] = tile[kt_sub * 32 + kstep * 16 + hi * 8 + j][dt * 32 + lo];
            const size_t kt = (size_t)(blockIdx.x * 2 + kt_sub);
            *(bf16x8*)&VP[(((size_t)b * N_ + n) * NT + kt) * 2048 + (size_t)t * 8] = o;
        }
    }
}

// ---------------------------------------------------------------------------
// Pass 1: Zrt packed = mask ? 1/sum_n exp2(s_n) : NaN, in pass2's exact
// fragment layout: Zrt[((b*NT + kt)*NT + qt)*1024 + c*256 + lane*4 + j]
// holds Z^-1 at (q = qt*32 + (lane&31), k = kt*32 + j + 8c + 4*(lane>>5)).
// Block = 4 waves; wave wv handles k-tiles ktA=(bx*4+wv)*2 and ktA+1 for
// q-tile by: SWAPPED QK^T (mfma(K,Q)) puts the C-layout directly in the
// packed fragment order. Q frags shared across the 2 k-tiles.
// Mask: coalesced AND-reduce + __all fast path (no per-element loads).
// ---------------------------------------------------------------------------
__global__ __launch_bounds__(256, 3) void pass1_z_kernel(
    const __bf16* __restrict__ QP, const __bf16* __restrict__ KP,
    const int* __restrict__ M, float* __restrict__ Zrt)
{
    const int tid  = threadIdx.x;
    const int wv   = tid >> 6;
    const int lane = tid & 63;
    const int lo   = lane & 31;
    const int hi   = lane >> 5;

    const int ktA = (blockIdx.x * 4 + wv) * 2;
    const int qt  = blockIdx.y;
    const int b   = blockIdx.z;
    const int k0A = ktA * TK;
    const int q0  = qt * TQ;

    const __bf16* Qp = QP + ((size_t)b * N_ * NT + qt) * 2048 + (size_t)lane * 8;
    const __bf16* Kp = KP + ((size_t)b * N_ * NT + ktA) * 2048 + (size_t)lane * 8;

    f32x16 zA = {}, zB = {};
    #pragma unroll 2
    for (int h = 0; h < N_; ++h) {
        const __bf16* Qh = Qp + (size_t)h * NT * 2048;
        const __bf16* Kh = Kp + (size_t)h * NT * 2048;
        bf16x8 qf[4], ka[4], kb[4];
        #pragma unroll
        for (int ks = 0; ks < 4; ++ks) {
            qf[ks] = *(const bf16x8*)(Qh + ks * 512);
            ka[ks] = *(const bf16x8*)(Kh + ks * 512);
            kb[ks] = *(const bf16x8*)(Kh + 2048 + ks * 512);
        }
        f32x16 sA = {}, sB = {};
        #pragma unroll
        for (int ks = 0; ks < 4; ++ks)
            sA = __builtin_amdgcn_mfma_f32_32x32x16_bf16(ka[ks], qf[ks], sA, 0, 0, 0);
        #pragma unroll
        for (int ks = 0; ks < 4; ++ks)
            sB = __builtin_amdgcn_mfma_f32_32x32x16_bf16(kb[ks], qf[ks], sB, 0, 0, 0);
        // s = (q.k)/8 * log2(e) (scale folded into Q); single v_exp_f32 each
        #pragma unroll
        for (int r = 0; r < 16; ++r) {
            zA[r] += __builtin_amdgcn_exp2f(sA[r]);
            zB[r] += __builtin_amdgcn_exp2f(sB[r]);
        }
    }

    // mask fast-path: AND-reduce all 32 q-rows x 64 k-cols (both tiles),
    // coalesced int2 loads (any full-coverage mapping works for the check).
    const size_t mb = (size_t)b * S_ * S_;
    int ok = 1;
    #pragma unroll
    for (int r = 0; r < 16; ++r) {
        const int2 mm = *(const int2*)&M[mb + (size_t)(q0 + 2 * r + hi) * S_ + k0A + 2 * lo];
        ok &= (mm.x != 0) & (mm.y != 0);
    }

    float vA[16], vB[16];
    #pragma unroll
    for (int r = 0; r < 16; ++r) {
        vA[r] = __builtin_amdgcn_rcpf(zA[r]);
        vB[r] = __builtin_amdgcn_rcpf(zB[r]);
    }

    if (!__all(ok)) {
        // rare slow path: per-element mask (scattered; correctness only).
        // mask==0: ref softmax over all-(-inf) heads -> NaN weights.
        #pragma unroll
        for (int r = 0; r < 16; ++r) {
            const int kap = (r & 3) + 8 * (r >> 2) + 4 * hi;
            const size_t rowb = mb + (size_t)(q0 + lo) * S_ + k0A;
            if (M[rowb + kap] == 0)      vA[r] = __builtin_nanf("");
            if (M[rowb + 32 + kap] == 0) vB[r] = __builtin_nanf("");
        }
    }

    float* ZA = Zrt + (((size_t)b * NT + ktA) * NT + qt) * 1024 + (size_t)lane * 4;
    float* ZB = ZA + (size_t)NT * 1024;   // kt = ktA+1
    #pragma unroll
    for (int c = 0; c < 4; ++c) {
        *(float4*)(ZA + c * 256) = make_float4(vA[4*c], vA[4*c+1], vA[4*c+2], vA[4*c+3]);
        *(float4*)(ZB + c * 256) = make_float4(vB[4*c], vB[4*c+1], vB[4*c+2], vB[4*c+3]);
    }
}

// ---------------------------------------------------------------------------
// Pass 2: out[b,n,q,:] = sum_k (exp2(s)*zr) V[k,:].
// Block = 256 thr = 4 waves, one (q-tile, head, b) per block; wave w sweeps
// k-tiles [w*16, w*16+16). Swapped QK^T (S^T = mfma(K,Q)) puts each q-row
// lane-local; cvt_pk + permlane32_swap build PV A-frags in-register.
// zr now loads as 4x b128 from the packed fragment layout (imm offsets).
// End: chunked (2x16-row) LDS combine of 4 k-partials, coalesced stores.
// ---------------------------------------------------------------------------
__global__ __launch_bounds__(256, 4) void pass2_av_kernel(
    const __bf16* __restrict__ QP, const __bf16* __restrict__ KP,
    const __bf16* __restrict__ VP, const float* __restrict__ Zrt,
    float* __restrict__ O)
{
    __shared__ __align__(16) float obuf[4][16 * D_];    // 16 KB, end combine

    const int tid  = threadIdx.x;
    const int wv   = tid >> 6;
    const int lane = tid & 63;
    const int lo   = lane & 31;
    const int hi   = lane >> 5;

    const int qt = blockIdx.x;
    const int n  = blockIdx.y;
    const int b  = blockIdx.z;
    const int q0 = qt * TQ;

    const __bf16* Qh = QP + (((size_t)b * N_ + n) * NT + qt) * 2048 + (size_t)lane * 8;
    const __bf16* Kh = KP + (((size_t)b * N_ + n) * NT) * 2048 + (size_t)lane * 8;
    const __bf16* Vh = VP + (((size_t)b * N_ + n) * NT) * 2048 + (size_t)lane * 8;
    const float*  Zh = Zrt + (size_t)b * NT * NT * 1024 + (size_t)lane * 4;

    // Q fragments (pre-scaled). B-operand of the swapped QK^T.
    bf16x8 qf[4];
    #pragma unroll
    for (int ks = 0; ks < 4; ++ks)
        qf[ks] = *(const bf16x8*)(Qh + ks * 512);

    f32x16 o0 = {};  // out cols d =  0..31 (C layout)
    f32x16 o1 = {};  // out cols d = 32..63

    #pragma unroll 2
    for (int t = 0; t < 16; ++t) {
        const int kt = wv * 16 + t;
        const __bf16* Kt = Kh + (size_t)kt * 2048;
        const __bf16* Vt = Vh + (size_t)kt * 2048;
        const float*  Zt = Zh + ((size_t)kt * NT + qt) * 1024;

        // zr: 4 coalesced b128 loads from packed layout; zr[4c+j] = chunk c, j.
        float4 z0 = *(const float4*)(Zt);
        float4 z1 = *(const float4*)(Zt + 256);
        float4 z2 = *(const float4*)(Zt + 512);
        float4 z3 = *(const float4*)(Zt + 768);
        float zr[16] = { z0.x, z0.y, z0.z, z0.w,  z1.x, z1.y, z1.z, z1.w,
                         z2.x, z2.y, z2.z, z2.w,  z3.x, z3.y, z3.z, z3.w };

        // V B-frags: lane-contiguous 1KB each
        bf16x8 vf[2][2];
        #pragma unroll
        for (int kstep = 0; kstep < 2; ++kstep)
            #pragma unroll
            for (int dt = 0; dt < 2; ++dt)
                vf[kstep][dt] = *(const bf16x8*)(Vt + (kstep * 2 + dt) * 512);

        // swapped QK^T: S^T[key=row][q=lo]; lane (lo,hi) holds scores of
        // q = q0+lo at keys kap(r,hi) = (r&3)+8*(r>>2)+4*hi (+kt*32)
        f32x16 s = {};
        #pragma unroll
        for (int ks = 0; ks < 4; ++ks) {
            bf16x8 kf = *(const bf16x8*)(Kt + ks * 512);
            s = __builtin_amdgcn_mfma_f32_32x32x16_bf16(kf, qf[ks], s, 0, 0, 0);
        }

        // w = exp2(s) * zr  (single v_exp_f32; NaN propagates for mask==0)
        float w[16];
        #pragma unroll
        for (int r = 0; r < 16; ++r) w[r] = __builtin_amdgcn_exp2f(s[r]) * zr[r];

        // pack to bf16 + cross-half redistribute -> exact PV A-fragments.
        #pragma unroll
        for (int kstep = 0; kstep < 2; ++kstep) {
            const int e = kstep * 8;
            unsigned int d0 = cvt_pk_bf16(w[e + 0], w[e + 1]);
            unsigned int d1 = cvt_pk_bf16(w[e + 2], w[e + 3]);
            unsigned int d2 = cvt_pk_bf16(w[e + 4], w[e + 5]);
            unsigned int d3 = cvt_pk_bf16(w[e + 6], w[e + 7]);
            permlane_swap(d0, d2);
            permlane_swap(d1, d3);
            uint32x4 u; u[0] = d0; u[1] = d1; u[2] = d2; u[3] = d3;
            const bf16x8 pa = __builtin_bit_cast(bf16x8, u);
            o0 = __builtin_amdgcn_mfma_f32_32x32x16_bf16(pa, vf[kstep][0], o0, 0, 0, 0);
            o1 = __builtin_amdgcn_mfma_f32_32x32x16_bf16(pa, vf[kstep][1], o1, 0, 0, 0);
        }
    }

    // k-split combine, chunked 2 x 16 rows (obuf 16KB). r<8 -> rows 0..15.
    #pragma unroll
    for (int half = 0; half < 2; ++half) {
        if (half) __syncthreads();   // protect obuf reuse
        #pragma unroll
        for (int r8 = 0; r8 < 8; ++r8) {
            const int r  = half * 8 + r8;
            const int lr = (r8 & 3) + 8 * (r8 >> 2) + 4 * hi;  // row - 16*half
            obuf[wv][lr * D_ + lo]      = o0[r];
            obuf[wv][lr * D_ + 32 + lo] = o1[r];
        }
        __syncthreads();
        const int e0 = tid * 4;          // 1024 f32 per half / 256 thr
        float a0 = 0.f, a1 = 0.f, a2 = 0.f, a3 = 0.f;
        #pragma unroll
        for (int w = 0; w < 4; ++w) {
            const float4 x = *(const float4*)&obuf[w][e0];
            a0 += x.x; a1 += x.y; a2 += x.z; a3 += x.w;
        }
        const int q = half * 16 + (e0 >> 6);
        const int d = e0 & 63;
        *(float4*)&O[(((size_t)b * N_ + n) * S_ + q0 + q) * (size_t)D_ + d]
            = make_float4(a0, a1, a2, a3);
    }
}

// ---------------------------------------------------------------------------
// Fallback (fp32 inputs): used only if ws is too small.
// ---------------------------------------------------------------------------
__global__ __launch_bounds__(1024) void sdpa_headsm_kernel(
    const float* __restrict__ Q, const float* __restrict__ K,
    const float* __restrict__ V, const int* __restrict__ M,
    float* __restrict__ O)
{
    __shared__ __align__(16) __bf16 pbuf[N_][TQ][40];

    const int tid  = threadIdx.x;
    const int n    = tid >> 6;
    const int lane = tid & 63;
    const int lo   = lane & 31;
    const int hi   = lane >> 5;

    const int q0 = blockIdx.x * TQ;
    const int b  = blockIdx.y;
    const int kz = blockIdx.z;
    const int FITERS = S_ / TK / 4;

    bf16x8 qf[4];
    {
        const float* qrow = Q + (((size_t)b * S_ + (size_t)(q0 + lo)) * N_ + n) * D_;
        #pragma unroll
        for (int ks = 0; ks < 4; ++ks) {
            const float* p = qrow + ks * 16 + hi * 8;
            float4 a0 = *(const float4*)(p);
            float4 a1 = *(const float4*)(p + 4);
            bf16x8 f;
            f[0] = (__bf16)a0.x; f[1] = (__bf16)a0.y;
            f[2] = (__bf16)a0.z; f[3] = (__bf16)a0.w;
            f[4] = (__bf16)a1.x; f[5] = (__bf16)a1.y;
            f[6] = (__bf16)a1.z; f[7] = (__bf16)a1.w;
            qf[ks] = f;
        }
    }

    f32x16 o0 = {};
    f32x16 o1 = {};

    for (int it = 0; it < FITERS; ++it) {
        const int k0 = (kz * FITERS + it) * TK;

        f32x16 s = {};
        #pragma unroll
        for (int ks = 0; ks < 4; ++ks) {
            const float* krow = K + (((size_t)b * S_ + (size_t)(k0 + lo)) * N_ + n) * D_
                                  + ks * 16 + hi * 8;
            float4 a0 = *(const float4*)(krow);
            float4 a1 = *(const float4*)(krow + 4);
            bf16x8 f;
            f[0] = (__bf16)a0.x; f[1] = (__bf16)a0.y;
            f[2] = (__bf16)a0.z; f[3] = (__bf16)a0.w;
            f[4] = (__bf16)a1.x; f[5] = (__bf16)a1.y;
            f[6] = (__bf16)a1.z; f[7] = (__bf16)a1.w;
            s = __builtin_amdgcn_mfma_f32_32x32x16_bf16(qf[ks], f, s, 0, 0, 0);
        }

        bf16x8 vf[2][2];
        #pragma unroll
        for (int kstep = 0; kstep < 2; ++kstep) {
            #pragma unroll
            for (int dt = 0; dt < 2; ++dt) {
                bf16x8 f;
                #pragma unroll
                for (int j = 0; j < 8; ++j) {
                    const int key = k0 + kstep * 16 + hi * 8 + j;
                    f[j] = (__bf16)V[(((size_t)b * S_ + key) * N_ + n) * D_ + dt * 32 + lo];
                }
                vf[kstep][dt] = f;
            }
        }

        #pragma unroll
        for (int r = 0; r < 16; ++r) {
            const int row = (r & 3) + 8 * (r >> 2) + 4 * hi;
            pbuf[n][row][lo] = (__bf16)__builtin_amdgcn_exp2f(s[r] * QSCALE);
        }

        __syncthreads();

        {
            const int tq = tid >> 5;
            const int tk = tid & 31;
            const int m = M[(size_t)b * S_ * S_ + (size_t)(q0 + tq) * S_ + (k0 + tk)];
            float pv[16];
            float sum = 0.f;
            #pragma unroll
            for (int j = 0; j < 16; ++j) { pv[j] = (float)pbuf[j][tq][tk]; sum += pv[j]; }
            const float rd = m ? (1.0f / sum) : __builtin_nanf("");
            #pragma unroll
            for (int j = 0; j < 16; ++j) pbuf[j][tq][tk] = (__bf16)(pv[j] * rd);
        }

        __syncthreads();

        #pragma unroll
        for (int kstep = 0; kstep < 2; ++kstep) {
            bf16x8 wf = *(const bf16x8*)&pbuf[n][lo][kstep * 16 + hi * 8];
            o0 = __builtin_amdgcn_mfma_f32_32x32x16_bf16(wf, vf[kstep][0], o0, 0, 0, 0);
            o1 = __builtin_amdgcn_mfma_f32_32x32x16_bf16(wf, vf[kstep][1], o1, 0, 0, 0);
        }

        __syncthreads();
    }

    #pragma unroll
    for (int r = 0; r < 16; ++r) {
        const int row = (r & 3) + 8 * (r >> 2) + 4 * hi;
        const size_t base = (((size_t)b * N_ + n) * S_ + (q0 + row)) * (size_t)D_;
        atomicAdd(&O[base + lo],      o0[r]);
        atomicAdd(&O[base + 32 + lo], o1[r]);
    }
}

extern "C" void kernel_launch(void* const* d_in, const int* in_sizes, int n_in,
                              void* d_out, int out_size, void* d_ws, size_t ws_size,
                              hipStream_t stream) {
    const float* Q = (const float*)d_in[0];
    const float* K = (const float*)d_in[1];
    const float* V = (const float*)d_in[2];
    const int*   M = (const int*)d_in[3];
    float* O = (float*)d_out;

    const size_t per  = (size_t)B_ * N_ * NT * 2048;       // 4,194,304 elements
    const size_t zcnt = (size_t)B_ * NT * NT * 1024;       // 8,388,608 elements
    const size_t need = 3 * per * sizeof(__bf16) + zcnt * sizeof(float);  // 56 MB

    if (ws_size >= need) {
        __bf16* QP = (__bf16*)d_ws;
        __bf16* KP = QP + per;
        __bf16* VP = KP + per;
        float*  Zrt = (float*)(VP + per);
        cvt_qk_pack_kernel<<<dim3(NT, N_, B_ * 2), dim3(256), 0, stream>>>(Q, K, QP, KP);
        cvt_v_pack_kernel<<<dim3(S_ / 64, N_, B_), dim3(256), 0, stream>>>(V, VP);
        pass1_z_kernel<<<dim3(NT / 8, NT, B_), dim3(256), 0, stream>>>(QP, KP, M, Zrt);
        pass2_av_kernel<<<dim3(NT, N_, B_), dim3(256), 0, stream>>>(QP, KP, VP, Zrt, O);
    } else {
        hipMemsetAsync(d_out, 0, (size_t)out_size * sizeof(float), stream);
        sdpa_headsm_kernel<<<dim3(S_ / TQ, B_, 4), dim3(1024), 0, stream>>>(Q, K, V, M, O);
    }
}